// Round 1
// baseline (39779.559 us; speedup 1.0000x reference)
//
#include <hip/hip_runtime.h>

#define BB 32
#define TT 2048
#define HH 256
#define NWG 128   // 64 slices x 2 layers
#define NT 512

__device__ __forceinline__ float sigm(float v) { return 1.0f / (1.0f + __expf(-v)); }

// Grid-wide barrier state lives in ws[0]; h double-buffer at ws+256.
__global__ __launch_bounds__(NT) void lstm_scan(
    const float* __restrict__ x,     // [B,T,H]
    const float* __restrict__ W,     // [L,4,H,2H]
    const float* __restrict__ bias,  // [L,4,H]
    float* out,                      // [B,T,H] + hT[B,H] + cT[B,H]
    float* __restrict__ hbuf,        // [L][2][B][H]
    int* __restrict__ barcnt)
{
    const int wg    = blockIdx.x;
    const int layer = wg >> 6;        // 0 or 1
    const int slice = wg & 63;
    const int hbase = slice << 2;     // 4 hidden units per wg
    const int tid   = threadIdx.x;
    const int b     = tid >> 4;       // 0..31
    const int u     = (tid >> 2) & 3; // hidden unit within slice
    const int g     = tid & 3;        // gate: 0=i 1=f 2=o 3=chat
    const int col   = hbase + u;

    __shared__ float wlds[16][516];   // [jj = g*4+u][512], pad 4 (2-way banks, 16B aligned)

    // Stage this wg's weight rows (contiguous in W): row j=(g,col) is W[l][g][col][0:512]
    for (int jj = 0; jj < 16; ++jj) {
        const float* wrow = W + (((size_t)layer * 4 + (jj >> 2)) * HH + (hbase + (jj & 3))) * (2 * HH);
        for (int k = tid; k < 2 * HH; k += NT) wlds[jj][k] = wrow[k];
    }
    __syncthreads();

    const int jj = g * 4 + u;
    const float bg = bias[((size_t)layer * 4 + g) * HH + col];
    const float4* wx4 = (const float4*)&wlds[jj][0];    // x-part weights (k<256)
    const float4* wh4 = (const float4*)&wlds[jj][256];  // h-part weights

    float c_state = 0.f;  // valid on g==0 lanes
    float h_def   = 0.f;  // layer-1 deferred output

    for (int s = 0; s <= TT; ++s) {
        const int t = (layer == 0) ? s : s - 1;  // layer 1 lags one grid step
        if (t >= 0 && t < TT) {
            const float* inp = (layer == 0) ? x : out;  // layer-1 input = h0 (stored in out)
            const float4* xr = (const float4*)(inp + (((size_t)b) * TT + t) * HH);
            float acc = bg, acc2 = 0.f;
            #pragma unroll 8
            for (int c4 = 0; c4 < 32; ++c4) {
                float4 a = xr[2 * c4], a2 = xr[2 * c4 + 1];
                float4 w = wx4[2 * c4], w2 = wx4[2 * c4 + 1];
                acc  += a.x * w.x + a.y * w.y + a.z * w.z + a.w * w.w;
                acc2 += a2.x * w2.x + a2.y * w2.y + a2.z * w2.z + a2.w * w2.w;
            }
            if (t > 0) {
                const float4* hr =
                    (const float4*)(hbuf + ((((size_t)layer) * 2 + (t & 1)) * BB + b) * HH);
                #pragma unroll 8
                for (int c4 = 0; c4 < 32; ++c4) {
                    float4 a = hr[2 * c4], a2 = hr[2 * c4 + 1];
                    float4 w = wh4[2 * c4], w2 = wh4[2 * c4 + 1];
                    acc  += a.x * w.x + a.y * w.y + a.z * w.z + a.w * w.w;
                    acc2 += a2.x * w2.x + a2.y * w2.y + a2.z * w2.z + a2.w * w2.w;
                }
            }
            acc += acc2;
            // gather the 4 gates of (b,u) onto the g==0 lane (lanes g..g^3 adjacent)
            float f_ = __shfl_xor(acc, 1);
            float o_ = __shfl_xor(acc, 2);
            float q_ = __shfl_xor(acc, 3);
            if (g == 0) {
                float ig = sigm(acc), fg = sigm(f_), og = sigm(o_), ch = tanhf(q_);
                c_state = fg * c_state + ig * ch;
                float hn = og * tanhf(c_state);
                // recurrent buffer, slot (t+1)&1 (read slot next step is t&1^1)
                hbuf[((((size_t)layer) * 2 + ((t + 1) & 1)) * BB + b) * HH + col] = hn;
                if (layer == 0) {
                    out[(((size_t)b) * TT + t) * HH + col] = hn;  // h0 -> out (layer-1 input)
                } else {
                    // defer by one step: others may still be reading slice t this grid step
                    if (t > 0) out[(((size_t)b) * TT + (t - 1)) * HH + col] = h_def;
                    h_def = hn;
                }
            }
        }
        // ---- grid barrier (release stores, arrive, acquire) ----
        __syncthreads();
        if (tid == 0) {
            __threadfence();                 // agent-scope release (wb to coherence point)
            atomicAdd(barcnt, 1);
            const int target = (s + 1) * NWG;
            while (__hip_atomic_load(barcnt, __ATOMIC_RELAXED, __HIP_MEMORY_SCOPE_AGENT) <
                   target) {}
            __threadfence();                 // acquire (invalidate stale L1/L2)
        }
        __syncthreads();
    }

    // epilogue: after final barrier everyone has read slice T-1; safe to write it + tail
    if (layer == 1 && g == 0) {
        out[(((size_t)b) * TT + (TT - 1)) * HH + col] = h_def;
        float* tail = out + (size_t)BB * TT * HH;
        tail[b * HH + col] = h_def;              // hT (last layer)
        tail[BB * HH + b * HH + col] = c_state;  // cT (last layer)
    }
}

extern "C" void kernel_launch(void* const* d_in, const int* in_sizes, int n_in,
                              void* d_out, int out_size, void* d_ws, size_t ws_size,
                              hipStream_t stream) {
    (void)in_sizes; (void)n_in; (void)out_size; (void)ws_size;
    const float* x    = (const float*)d_in[0];
    const float* W    = (const float*)d_in[1];
    const float* bias = (const float*)d_in[2];
    float* out  = (float*)d_out;
    int*   barc = (int*)d_ws;
    float* hbuf = (float*)((char*)d_ws + 256);  // L*2*B*H floats = 128 KB

    hipMemsetAsync(d_ws, 0, 256, stream);  // zero barrier counter every call (deterministic)
    hipLaunchKernelGGL(lstm_scan, dim3(NWG), dim3(NT), 0, stream, x, W, bias, out, hbuf, barc);
}

// Round 2
// 33441.342 us; speedup vs baseline: 1.1895x; 1.1895x over previous
//
#include <hip/hip_runtime.h>

#define BB 32
#define TT 2048
#define HH 256
#define NT 512

__device__ __forceinline__ float sigm(float v) { return 1.0f / (1.0f + __expf(-v)); }

__device__ __forceinline__ int aload(int* p) {
  return __hip_atomic_load(p, __ATOMIC_RELAXED, __HIP_MEMORY_SCOPE_AGENT);
}
__device__ __forceinline__ void astore(int* p, int v) {
  __hip_atomic_store(p, v, __ATOMIC_RELAXED, __HIP_MEMORY_SCOPE_AGENT);
}

// sync layout (ints): [0..63] layer0 slots, [64..127] layer1 slots,
//                     [256] epoch0, [320] epoch1
__global__ __launch_bounds__(NT) void lstm_scan(
    const float* __restrict__ x,     // [B,T,H]
    const float* __restrict__ W,     // [L,4,H,2H]
    const float* __restrict__ bias,  // [L,4,H]
    float* out,                      // [B,T,H] + hT[B,H] + cT[B,H]
    float* __restrict__ hbuf,        // [L][2][B][H]
    int* __restrict__ sync)
{
    const int wg    = blockIdx.x;
    const int layer = wg >> 6;        // 0 or 1
    const int slice = wg & 63;
    const int hbase = slice << 2;     // 4 hidden units per wg
    const int tid   = threadIdx.x;
    const int b     = tid >> 4;       // 0..31
    const int u     = (tid >> 2) & 3; // hidden unit within slice
    const int g     = tid & 3;        // gate: 0=i 1=f 2=o 3=chat
    const int col   = hbase + u;

    int* slots  = sync + layer * 64;
    int* epoch0 = sync + 256;
    int* epoch1 = sync + 320;
    int* myep   = layer ? epoch1 : epoch0;

    __shared__ float wlds[16][516];   // [jj = g*4+u][512], +4 pad

    for (int jj = 0; jj < 16; ++jj) {
        const float* wrow = W + (((size_t)layer * 4 + (jj >> 2)) * HH + (hbase + (jj & 3))) * (2 * HH);
        for (int k = tid; k < 2 * HH; k += NT) wlds[jj][k] = wrow[k];
    }
    __syncthreads();

    const int jj = g * 4 + u;
    const float bg = bias[((size_t)layer * 4 + g) * HH + col];
    const float4* wx4 = (const float4*)&wlds[jj][0];    // x-part weights (k<256)
    const float4* wh4 = (const float4*)&wlds[jj][256];  // h-part weights

    float c_state = 0.f;  // valid on g==0 lanes
    float h_def   = 0.f;  // layer-1 deferred output

    for (int t = 0; t < TT; ++t) {
        // ---- phase A: wait for own-layer epoch t (prev step done) + producer ----
        if (tid == 0) {
            if (layer == 0) {
                while (aload(epoch0) < t) __builtin_amdgcn_s_sleep(1);
            } else {
                while (aload(epoch1) < t) __builtin_amdgcn_s_sleep(1);
                while (aload(epoch0) < t + 1) __builtin_amdgcn_s_sleep(1);
            }
            __threadfence();  // acquire
        }
        __syncthreads();

        // ---- phase B: compute h(t) ----
        const float* inp = (layer == 0) ? x : out;  // layer-1 input = h0 (stored in out)
        const float4* xr = (const float4*)(inp + (((size_t)b) * TT + t) * HH);
        float acc = bg, acc2 = 0.f;
        #pragma unroll 8
        for (int c4 = 0; c4 < 32; ++c4) {
            float4 a = xr[2 * c4], a2 = xr[2 * c4 + 1];
            float4 w = wx4[2 * c4], w2 = wx4[2 * c4 + 1];
            acc  += a.x * w.x + a.y * w.y + a.z * w.z + a.w * w.w;
            acc2 += a2.x * w2.x + a2.y * w2.y + a2.z * w2.z + a2.w * w2.w;
        }
        if (t > 0) {
            const float4* hr =
                (const float4*)(hbuf + ((((size_t)layer) * 2 + (t & 1)) * BB + b) * HH);
            #pragma unroll 8
            for (int c4 = 0; c4 < 32; ++c4) {
                float4 a = hr[2 * c4], a2 = hr[2 * c4 + 1];
                float4 w = wh4[2 * c4], w2 = wh4[2 * c4 + 1];
                acc  += a.x * w.x + a.y * w.y + a.z * w.z + a.w * w.w;
                acc2 += a2.x * w2.x + a2.y * w2.y + a2.z * w2.z + a2.w * w2.w;
            }
        }
        acc += acc2;
        float f_ = __shfl_xor(acc, 1);
        float o_ = __shfl_xor(acc, 2);
        float q_ = __shfl_xor(acc, 3);
        if (g == 0) {
            float ig = sigm(acc), fg = sigm(f_), og = sigm(o_), ch = tanhf(q_);
            c_state = fg * c_state + ig * ch;
            float hn = og * tanhf(c_state);
            hbuf[((((size_t)layer) * 2 + ((t + 1) & 1)) * BB + b) * HH + col] = hn;
            if (layer == 0) {
                out[(((size_t)b) * TT + t) * HH + col] = hn;
            } else {
                if (t > 0) out[(((size_t)b) * TT + (t - 1)) * HH + col] = h_def;
                h_def = hn;
            }
        }

        // ---- phase C: arrive (no RMW) + master publishes epoch ----
        __syncthreads();
        if (tid == 0) {
            __threadfence();  // release our h/out writes
            astore(&slots[slice], t + 1);
        }
        if (slice == 0 && tid < 64) {
            for (;;) {
                int v = aload(&slots[tid]);
                if (__all(v >= t + 1)) break;
                __builtin_amdgcn_s_sleep(1);
            }
            if (tid == 0) {
                __threadfence();
                astore(myep, t + 1);
            }
        }
    }

    // epilogue: wait for all layer-1 WGs to finish reading out(T-1), then write it
    if (layer == 1) {
        if (tid == 0) {
            while (aload(epoch1) < TT) __builtin_amdgcn_s_sleep(1);
            __threadfence();
        }
        __syncthreads();
        if (g == 0) {
            out[(((size_t)b) * TT + (TT - 1)) * HH + col] = h_def;
            float* tail = out + (size_t)BB * TT * HH;
            tail[b * HH + col] = h_def;              // hT (last layer)
            tail[BB * HH + b * HH + col] = c_state;  // cT (last layer)
        }
    }
}

extern "C" void kernel_launch(void* const* d_in, const int* in_sizes, int n_in,
                              void* d_out, int out_size, void* d_ws, size_t ws_size,
                              hipStream_t stream) {
    (void)in_sizes; (void)n_in; (void)out_size; (void)ws_size;
    const float* x    = (const float*)d_in[0];
    const float* W    = (const float*)d_in[1];
    const float* bias = (const float*)d_in[2];
    float* out  = (float*)d_out;
    int*   sync = (int*)d_ws;
    float* hbuf = (float*)((char*)d_ws + 4096);  // L*2*B*H floats = 128 KB

    hipMemsetAsync(d_ws, 0, 4096, stream);  // zero slots + epochs (deterministic)
    hipLaunchKernelGGL(lstm_scan, dim3(128), dim3(NT), 0, stream, x, W, bias, out, hbuf, sync);
}

// Round 3
// 26073.196 us; speedup vs baseline: 1.5257x; 1.2826x over previous
//
#include <hip/hip_runtime.h>

#define BB 32
#define TT 2048
#define HH 256
#define NT 512

typedef unsigned long long ull;

__device__ __forceinline__ float sigm(float v) { return 1.0f / (1.0f + __expf(-v)); }

__device__ __forceinline__ int aload(const int* p) {
  return __hip_atomic_load(p, __ATOMIC_RELAXED, __HIP_MEMORY_SCOPE_AGENT);
}
__device__ __forceinline__ void astore(int* p, int v) {
  __hip_atomic_store(p, v, __ATOMIC_RELAXED, __HIP_MEMORY_SCOPE_AGENT);
}
__device__ __forceinline__ ull aload64(const ull* p) {
  return __hip_atomic_load(p, __ATOMIC_RELAXED, __HIP_MEMORY_SCOPE_AGENT);
}
__device__ __forceinline__ void astoref(float* p, float v) {
  __hip_atomic_store((unsigned*)p, __float_as_uint(v), __ATOMIC_RELAXED, __HIP_MEMORY_SCOPE_AGENT);
}

// sync layout (ints): [0..63] layer0 slots, [64..127] layer1 slots
__global__ __launch_bounds__(NT) void lstm_scan(
    const float* __restrict__ x,     // [B,T,H]
    const float* __restrict__ W,     // [L,4,H,2H]
    const float* __restrict__ bias,  // [L,4,H]
    float* out,                      // [B,T,H] + hT[B,H] + cT[B,H]
    float* hbuf,                     // [L][2][B][H]
    int* sync)
{
    const int wg    = blockIdx.x;
    const int layer = wg >> 6;        // 0 or 1
    const int slice = wg & 63;
    const int hbase = slice << 2;     // 4 hidden units per wg
    const int tid   = threadIdx.x;
    const int b     = tid >> 4;       // 0..31
    const int u     = (tid >> 2) & 3; // hidden unit within slice
    const int g     = tid & 3;        // gate: 0=i 1=f 2=o 3=chat
    const int col   = hbase + u;

    int* slots0 = sync;
    int* slots1 = sync + 64;
    int* sown   = layer ? slots1 : slots0;

    __shared__ float wlds[16][516];   // weight rows, +4 pad
    __shared__ float inp[BB][260];    // staged input row-block (x_t or h0(t))
    __shared__ float hrec[BB][260];   // staged recurrent h(t-1)

    for (int r = 0; r < 16; ++r) {
        const float* wrow = W + (((size_t)layer * 4 + (r >> 2)) * HH + (hbase + (r & 3))) * (2 * HH);
        for (int k = tid; k < 2 * HH; k += NT) wlds[r][k] = wrow[k];
    }
    __syncthreads();

    const int jj = g * 4 + u;
    const float bg = bias[((size_t)layer * 4 + g) * HH + col];
    const float4* wx4 = (const float4*)&wlds[jj][0];    // x-part (k<256)
    const float4* wh4 = (const float4*)&wlds[jj][256];  // h-part

    // staging map: thread stages 64B of each 32KB block: batch sb, floats [sk, sk+16)
    const int sb = tid & 31;
    const int sk = (tid >> 5) << 4;

    float c_state = 0.f;  // valid on g==0 lanes
    float h_def   = 0.f;  // layer-1 deferred output

    for (int t = 0; t < TT; ++t) {
        // ---- phase A: self-observe slot arrays (no master, no fences) ----
        if (tid < 64) {
            for (;;) {
                int v = aload(&sown[tid]);
                if (__all(v >= t)) break;
                __builtin_amdgcn_s_sleep(1);
            }
        } else if (layer == 1 && tid < 128) {
            for (;;) {
                int v = aload(&slots0[tid - 64]);
                if (__all(v >= t + 1)) break;
                __builtin_amdgcn_s_sleep(1);
            }
        }
        __syncthreads();

        // ---- phase B: cooperative stage into LDS ----
        if (layer == 0) {
            const float4* src = (const float4*)(x + ((size_t)sb * TT + t) * HH + sk);
            float4 a0 = src[0], a1 = src[1], a2 = src[2], a3 = src[3];
            float4* dst = (float4*)&inp[sb][sk];
            dst[0] = a0; dst[1] = a1; dst[2] = a2; dst[3] = a3;
        } else {
            const ull* src = (const ull*)(out + ((size_t)sb * TT + t) * HH + sk);
            ull v[8];
            #pragma unroll
            for (int j = 0; j < 8; ++j) v[j] = aload64(&src[j]);
            ull* dst = (ull*)&inp[sb][sk];
            #pragma unroll
            for (int j = 0; j < 8; ++j) dst[j] = v[j];
        }
        if (t > 0) {
            const ull* src = (const ull*)(hbuf + (((size_t)layer * 2 + (t & 1)) * BB + sb) * HH + sk);
            ull v[8];
            #pragma unroll
            for (int j = 0; j < 8; ++j) v[j] = aload64(&src[j]);
            ull* dst = (ull*)&hrec[sb][sk];
            #pragma unroll
            for (int j = 0; j < 8; ++j) dst[j] = v[j];
        }
        __syncthreads();

        // ---- phase C: gates from LDS ----
        const float4* xr = (const float4*)&inp[b][0];
        float acc = bg, acc2 = 0.f;
        #pragma unroll 8
        for (int c4 = 0; c4 < 32; ++c4) {
            float4 a = xr[2 * c4], a2v = xr[2 * c4 + 1];
            float4 w = wx4[2 * c4], w2 = wx4[2 * c4 + 1];
            acc  += a.x * w.x + a.y * w.y + a.z * w.z + a.w * w.w;
            acc2 += a2v.x * w2.x + a2v.y * w2.y + a2v.z * w2.z + a2v.w * w2.w;
        }
        if (t > 0) {
            const float4* hr = (const float4*)&hrec[b][0];
            #pragma unroll 8
            for (int c4 = 0; c4 < 32; ++c4) {
                float4 a = hr[2 * c4], a2v = hr[2 * c4 + 1];
                float4 w = wh4[2 * c4], w2 = wh4[2 * c4 + 1];
                acc  += a.x * w.x + a.y * w.y + a.z * w.z + a.w * w.w;
                acc2 += a2v.x * w2.x + a2v.y * w2.y + a2v.z * w2.z + a2v.w * w2.w;
            }
        }
        acc += acc2;
        float f_ = __shfl_xor(acc, 1);
        float o_ = __shfl_xor(acc, 2);
        float q_ = __shfl_xor(acc, 3);
        if (g == 0) {
            float ig = sigm(acc), fg = sigm(f_), og = sigm(o_), ch = tanhf(q_);
            c_state = fg * c_state + ig * ch;
            float hn = og * tanhf(c_state);
            astoref(&hbuf[(((size_t)layer * 2 + ((t + 1) & 1)) * BB + b) * HH + col], hn);
            if (layer == 0) {
                astoref(&out[((size_t)b * TT + t) * HH + col], hn);  // h0 -> layer-1 input
            } else {
                if (t > 0) out[((size_t)b * TT + (t - 1)) * HH + col] = h_def;  // plain store
                h_def = hn;
            }
        }

        // ---- phase D: arrive. waitcnt(0) = release for write-through stores ----
        asm volatile("s_waitcnt vmcnt(0)" ::: "memory");
        __syncthreads();
        if (tid == 0) astore(&sown[slice], t + 1);
    }

    // epilogue: all layer-1 WGs must pass step T-1 reads before out[T-1] overwrite
    if (layer == 1) {
        if (tid < 64) {
            for (;;) {
                int v = aload(&slots1[tid]);
                if (__all(v >= TT)) break;
                __builtin_amdgcn_s_sleep(1);
            }
        }
        __syncthreads();
        if (g == 0) {
            out[((size_t)b * TT + (TT - 1)) * HH + col] = h_def;
            float* tail = out + (size_t)BB * TT * HH;
            tail[b * HH + col] = h_def;              // hT (last layer)
            tail[BB * HH + b * HH + col] = c_state;  // cT (last layer)
        }
    }
}

extern "C" void kernel_launch(void* const* d_in, const int* in_sizes, int n_in,
                              void* d_out, int out_size, void* d_ws, size_t ws_size,
                              hipStream_t stream) {
    (void)in_sizes; (void)n_in; (void)out_size; (void)ws_size;
    const float* x    = (const float*)d_in[0];
    const float* W    = (const float*)d_in[1];
    const float* bias = (const float*)d_in[2];
    float* out  = (float*)d_out;
    int*   sync = (int*)d_ws;
    float* hbuf = (float*)((char*)d_ws + 4096);  // L*2*B*H floats = 128 KB

    hipMemsetAsync(d_ws, 0, 4096, stream);  // zero slots (deterministic)
    hipLaunchKernelGGL(lstm_scan, dim3(128), dim3(NT), 0, stream, x, W, bias, out, hbuf, sync);
}